// Round 1
// baseline (2674.408 us; speedup 1.0000x reference)
//
#include <hip/hip_runtime.h>
#include <cstdint>
#include <cstddef>

// Problem constants (fixed by setup_inputs):
static constexpr int BB = 32, CC = 1024, LL = 4096, KK = 4, NCLS = 10;
static constexpr long long NTOT = 1LL * BB * CC * LL;   // 134,217,728
static constexpr int ROWS = BB * CC;                     // 32,768

// ws layout (floats):
//  f[0]=amax_x  f[1]=amax_convw  f[2]=amax_conv  f[3]=amax_silu  f[4]=amax_pool  f[5]=amax_linw
//  f[8..263]   = lut2 (256 entries)
//  f[1024..]   = pooled [32*1024]
//  byte 135168.. = optional qc int8 buffer (NTOT bytes) if ws_size permits

__device__ __forceinline__ float fq_(float x, float s) {
  // fake_quant forward: clip(rint(x/s), -128, 127) * s   (rint = half-to-even, matches jnp.round)
  float q = rintf(x / s);
  q = fminf(fmaxf(q, -128.f), 127.f);
  return q * s;
}
__device__ __forceinline__ float qlvl_(float x, float s) {
  float q = rintf(x / s);
  return fminf(fmaxf(q, -128.f), 127.f);
}

__global__ void init_k(unsigned* slots) {
  if (threadIdx.x < 8) slots[threadIdx.x] = 0u;
}

__global__ __launch_bounds__(256) void amax_k(const float* __restrict__ p, long long n4, unsigned* __restrict__ slot) {
  __shared__ float red[256];
  float m = 0.f;
  long long i = (long long)blockIdx.x * blockDim.x + threadIdx.x;
  long long stride = (long long)gridDim.x * blockDim.x;
  const float4* p4 = (const float4*)p;
  for (; i < n4; i += stride) {
    float4 v = p4[i];
    m = fmaxf(m, fmaxf(fmaxf(fabsf(v.x), fabsf(v.y)), fmaxf(fabsf(v.z), fabsf(v.w))));
  }
  int t = threadIdx.x;
  red[t] = m; __syncthreads();
  for (int s = 128; s > 0; s >>= 1) { if (t < s) red[t] = fmaxf(red[t], red[t + s]); __syncthreads(); }
  if (t == 0) atomicMax(slot, __float_as_uint(red[0]));
}

// Load this thread's 16 quantized x values plus 3 predecessors (causal K=4 stencil).
__device__ __forceinline__ void load_qx19(const float* __restrict__ xr, int t0, float s_x, float* q) {
  if (t0 == 0) {
    q[0] = 0.f; q[1] = 0.f; q[2] = 0.f;   // causal zero pad (pad applied AFTER input quant in ref)
  } else {
    float4 p = *(const float4*)(xr + t0 - 4);
    q[0] = fq_(p.y, s_x); q[1] = fq_(p.z, s_x); q[2] = fq_(p.w, s_x);
  }
#pragma unroll
  for (int j = 0; j < 4; ++j) {
    float4 v = *(const float4*)(xr + t0 + 4 * j);
    q[3 + 4 * j] = fq_(v.x, s_x); q[4 + 4 * j] = fq_(v.y, s_x);
    q[5 + 4 * j] = fq_(v.z, s_x); q[6 + 4 * j] = fq_(v.w, s_x);
  }
}

__device__ __forceinline__ void load_wq(const float* __restrict__ w, int c, float s_w,
                                        float& w0, float& w1, float& w2, float& w3) {
  w0 = fq_(w[c * 4 + 0], s_w); w1 = fq_(w[c * 4 + 1], s_w);
  w2 = fq_(w[c * 4 + 2], s_w); w3 = fq_(w[c * 4 + 3], s_w);
}

// Pass 2: conv output amax (incl. bias).
__global__ __launch_bounds__(256) void conv_amax_k(const float* __restrict__ x, const float* __restrict__ w,
    const float* __restrict__ bias, const float* __restrict__ wsf, unsigned* __restrict__ slot) {
  __shared__ float red[256];
  int row = blockIdx.x, c = row & (CC - 1);
  float s_x = wsf[0] / 127.f + 1e-8f, s_w = wsf[1] / 127.f + 1e-8f;
  float w0, w1, w2, w3; load_wq(w, c, s_w, w0, w1, w2, w3);
  float bc = bias[c];
  const float* xr = x + 1LL * row * LL;
  int t0 = threadIdx.x * 16;
  float q[19]; load_qx19(xr, t0, s_x, q);
  float m = 0.f;
#pragma unroll
  for (int j = 0; j < 16; ++j) {
    float h = q[j] * w0 + q[j + 1] * w1 + q[j + 2] * w2 + q[j + 3] * w3 + bc;
    m = fmaxf(m, fabsf(h));
  }
  int t = threadIdx.x;
  red[t] = m; __syncthreads();
  for (int s = 128; s > 0; s >>= 1) { if (t < s) red[t] = fmaxf(red[t], red[t + s]); __syncthreads(); }
  if (t == 0) atomicMax(slot, __float_as_uint(red[0]));
}

// Pass 3: conv again -> int8 level qc, silu amax; optional qc store (if ws big enough).
__global__ __launch_bounds__(256) void conv_silu_k(const float* __restrict__ x, const float* __restrict__ w,
    const float* __restrict__ bias, const float* __restrict__ wsf, unsigned* __restrict__ slot,
    signed char* __restrict__ qc) {
  __shared__ float red[256];
  int row = blockIdx.x, c = row & (CC - 1);
  float s_x = wsf[0] / 127.f + 1e-8f, s_w = wsf[1] / 127.f + 1e-8f, s_c = wsf[2] / 127.f + 1e-8f;
  float w0, w1, w2, w3; load_wq(w, c, s_w, w0, w1, w2, w3);
  float bc = bias[c];
  const float* xr = x + 1LL * row * LL;
  int t0 = threadIdx.x * 16;
  float q[19]; load_qx19(xr, t0, s_x, q);
  float m = 0.f;
  union { int4 v; signed char ch[16]; } pk;
#pragma unroll
  for (int j = 0; j < 16; ++j) {
    float h = q[j] * w0 + q[j + 1] * w1 + q[j + 2] * w2 + q[j + 3] * w3 + bc;
    float qi = qlvl_(h, s_c);
    float h1 = qi * s_c;                        // conv_quant output value
    float sg = 1.f / (1.f + expf(-h1));
    float y = h1 * sg;                          // SiLU
    m = fmaxf(m, fabsf(y));
    pk.ch[j] = (signed char)(int)qi;
  }
  if (qc) *(int4*)(qc + 1LL * row * LL + t0) = pk.v;
  int t = threadIdx.x;
  red[t] = m; __syncthreads();
  for (int s = 128; s > 0; s >>= 1) { if (t < s) red[t] = fmaxf(red[t], red[t + s]); __syncthreads(); }
  if (t == 0) atomicMax(slot, __float_as_uint(red[0]));
}

// Pass 4 (tiny): build 256-entry LUT for conv-level -> double-fake-quanted SiLU value.
// s2 derived analytically: max|j| = rint(amax_y/s1) (rint monotone & symmetric -> exact).
__global__ void lut_k(const float* __restrict__ wsf, float* __restrict__ lut2) {
  float s_c = wsf[2] / 127.f + 1e-8f;
  float amax_y = wsf[3];
  float s1 = amax_y / 127.f + 1e-8f;
  float maxj = fminf(fmaxf(rintf(amax_y / s1), -128.f), 127.f);
  float s2 = (maxj * s1) / 127.f + 1e-8f;
  int i = threadIdx.x;                          // 0..255 -> level i-128
  float v = (float)(i - 128) * s_c;
  float sg = 1.f / (1.f + expf(-v));
  float y = v * sg;
  float y1 = fq_(y, s1);
  float y2 = fq_(y1, s2);
  lut2[i] = y2;
}

// Pass 5a: pool from stored qc (134 MB read instead of 536 MB).
__global__ __launch_bounds__(256) void pool_qc_k(const signed char* __restrict__ qc,
    const float* __restrict__ lut2g, float* __restrict__ pooled, unsigned* __restrict__ slot) {
  __shared__ float lut[256];
  __shared__ float red[256];
  lut[threadIdx.x] = lut2g[threadIdx.x];
  int row = blockIdx.x;
  union { int4 v; signed char ch[16]; } pk;
  pk.v = *(const int4*)(qc + 1LL * row * LL + threadIdx.x * 16);
  __syncthreads();
  float sum = 0.f;
#pragma unroll
  for (int k = 0; k < 16; ++k) sum += lut[(int)pk.ch[k] + 128];
  int t = threadIdx.x;
  red[t] = sum; __syncthreads();
  for (int s = 128; s > 0; s >>= 1) { if (t < s) red[t] += red[t + s]; __syncthreads(); }
  if (t == 0) {
    float pv = red[0] * (1.f / (float)LL);
    pooled[row] = pv;
    atomicMax(slot, __float_as_uint(fabsf(pv)));
  }
}

// Pass 5b fallback: recompute conv from x and pool via LUT (no big ws needed).
__global__ __launch_bounds__(256) void pool_conv_k(const float* __restrict__ x, const float* __restrict__ w,
    const float* __restrict__ bias, const float* __restrict__ wsf, const float* __restrict__ lut2g,
    float* __restrict__ pooled, unsigned* __restrict__ slot) {
  __shared__ float lut[256];
  __shared__ float red[256];
  lut[threadIdx.x] = lut2g[threadIdx.x];
  int row = blockIdx.x, c = row & (CC - 1);
  float s_x = wsf[0] / 127.f + 1e-8f, s_w = wsf[1] / 127.f + 1e-8f, s_c = wsf[2] / 127.f + 1e-8f;
  float w0, w1, w2, w3; load_wq(w, c, s_w, w0, w1, w2, w3);
  float bc = bias[c];
  const float* xr = x + 1LL * row * LL;
  int t0 = threadIdx.x * 16;
  float q[19]; load_qx19(xr, t0, s_x, q);
  __syncthreads();
  float sum = 0.f;
#pragma unroll
  for (int j = 0; j < 16; ++j) {
    float h = q[j] * w0 + q[j + 1] * w1 + q[j + 2] * w2 + q[j + 3] * w3 + bc;
    sum += lut[(int)qlvl_(h, s_c) + 128];
  }
  int t = threadIdx.x;
  red[t] = sum; __syncthreads();
  for (int s = 128; s > 0; s >>= 1) { if (t < s) red[t] += red[t + s]; __syncthreads(); }
  if (t == 0) {
    float pv = red[0] * (1.f / (float)LL);
    pooled[row] = pv;
    atomicMax(slot, __float_as_uint(fabsf(pv)));
  }
}

// Pass 6 (tiny): fake-quant pooled & lin_w, 32x10 logits.
__global__ __launch_bounds__(256) void head_k(const float* __restrict__ pooled, const float* __restrict__ lw,
    const float* __restrict__ lb, const float* __restrict__ wsf, float* __restrict__ out) {
  __shared__ float red[256];
  int b = blockIdx.x / NCLS, n = blockIdx.x % NCLS;
  float s_p = wsf[4] / 127.f + 1e-8f, s_l = wsf[5] / 127.f + 1e-8f;
  float sum = 0.f;
  for (int ci = threadIdx.x; ci < CC; ci += 256)
    sum += fq_(pooled[b * CC + ci], s_p) * fq_(lw[n * CC + ci], s_l);
  int t = threadIdx.x;
  red[t] = sum; __syncthreads();
  for (int s = 128; s > 0; s >>= 1) { if (t < s) red[t] += red[t + s]; __syncthreads(); }
  if (t == 0) out[b * NCLS + n] = red[0] + lb[n];
}

extern "C" void kernel_launch(void* const* d_in, const int* in_sizes, int n_in,
                              void* d_out, int out_size, void* d_ws, size_t ws_size,
                              hipStream_t stream) {
  const float* x  = (const float*)d_in[0];
  const float* cw = (const float*)d_in[1];
  const float* cb = (const float*)d_in[2];
  const float* lw = (const float*)d_in[3];
  const float* lb = (const float*)d_in[4];
  float* out = (float*)d_out;
  float* wsf = (float*)d_ws;
  unsigned* slots = (unsigned*)d_ws;
  float* lut2 = wsf + 8;
  float* pooled = wsf + 1024;
  size_t base = (size_t)(1024 + ROWS) * sizeof(float);   // 135,168 B (16B aligned)
  signed char* qc = nullptr;
  if (ws_size >= base + (size_t)NTOT + 16) qc = (signed char*)d_ws + base;

  hipLaunchKernelGGL(init_k, dim3(1), dim3(64), 0, stream, slots);
  hipLaunchKernelGGL(amax_k, dim3(4096), dim3(256), 0, stream, x, NTOT / 4, slots + 0);
  hipLaunchKernelGGL(amax_k, dim3(4), dim3(256), 0, stream, cw, (long long)(CC * KK / 4), slots + 1);
  hipLaunchKernelGGL(amax_k, dim3(10), dim3(256), 0, stream, lw, (long long)(NCLS * CC / 4), slots + 5);
  hipLaunchKernelGGL(conv_amax_k, dim3(ROWS), dim3(256), 0, stream, x, cw, cb, wsf, slots + 2);
  hipLaunchKernelGGL(conv_silu_k, dim3(ROWS), dim3(256), 0, stream, x, cw, cb, wsf, slots + 3, qc);
  hipLaunchKernelGGL(lut_k, dim3(1), dim3(256), 0, stream, wsf, lut2);
  if (qc) {
    hipLaunchKernelGGL(pool_qc_k, dim3(ROWS), dim3(256), 0, stream, qc, lut2, pooled, slots + 4);
  } else {
    hipLaunchKernelGGL(pool_conv_k, dim3(ROWS), dim3(256), 0, stream, x, cw, cb, wsf, lut2, pooled, slots + 4);
  }
  hipLaunchKernelGGL(head_k, dim3(BB * NCLS), dim3(256), 0, stream, pooled, lb ? lw : lw, lb, wsf, out);
}

// Round 2
// 969.710 us; speedup vs baseline: 2.7579x; 2.7579x over previous
//
#include <hip/hip_runtime.h>
#include <cstdint>
#include <cstddef>

// MambaConv1DTest: fake-quant -> depthwise causal conv1d(K=4) -> fake-quant ->
// SiLU -> 2x fake-quant -> mean over L -> fake-quant -> 10-class linear head.
//
// Structure (all amax reductions are atomic-FREE: block partials to distinct
// slots + tiny fin kernels; R0 lesson: 32768 same-address device atomicMax
// serialized = ~1ms). LDS LUTs replicated 32x -> conflict-free.
//  small_k : amax(conv_w), amax(lin_w)                       (tiny)
//  p1_k    : amax(x)             536 MB read                 -> bm0[8192]
//  fin_k   : bm0 -> wsf[0]
//  p2_k    : quantize x -> qx int8 store, conv, amax|h|      536r+134w -> bm1
//  finA_k  : bm1 -> wsf[2]; build absY[256] = |silu(lvl*s_c)|
//  p3_k    : conv from qx levels (exact int fp32), qc int8,  134r+134w -> bm2
//            amax|silu| via conflict-free replicated LUT (no expf hot path)
//  finL_k  : bm2 -> wsf[3]; build pool LUT lut2[256]
//  p5_k    : mean-pool via replicated LUT from qc            134r      -> bm3
//  fin_k   : bm3 -> wsf[4]
//  head_k  : logits
// Ideal bytes ~1.6 GB -> ~260 us at 6.3 TB/s.

static constexpr int BB = 32, CC = 1024, LL = 4096, NCLS = 10;
static constexpr long long NTOT = 1LL * BB * CC * LL;   // 134,217,728
static constexpr int ROWS = BB * CC;                     // 32,768
static constexpr int G1 = 8192, G2 = 8192, G3 = 8192, G5 = 2048;

// ws float offsets
static constexpr int OF_LUT2 = 8;      // 256
static constexpr int OF_ABSY = 264;    // 256
static constexpr int OF_POOL = 1024;   // 32768
static constexpr int OF_BM0  = 40960;  // 8192
static constexpr int OF_BM1  = 49152;  // 8192
static constexpr int OF_BM2  = 57344;  // 8192
static constexpr int OF_BM3  = 65536;  // 2048
static constexpr size_t OFFQ = 67584ull * 4ull;  // byte offset of qx (16B aligned)

__device__ __forceinline__ float qlvl_mul(float x, float rs) {
  return fminf(fmaxf(rintf(x * rs), -128.f), 127.f);
}
__device__ __forceinline__ float qlvl_div(float x, float s) {
  return fminf(fmaxf(rintf(x / s), -128.f), 127.f);
}
__device__ __forceinline__ float fq_div(float x, float s) {
  return qlvl_div(x, s) * s;
}
__device__ __forceinline__ float wred_max(float m) {
#pragma unroll
  for (int o = 32; o; o >>= 1) m = fmaxf(m, __shfl_xor(m, o));
  return m;
}
__device__ __forceinline__ float wred_sum(float s) {
#pragma unroll
  for (int o = 32; o; o >>= 1) s += __shfl_xor(s, o);
  return s;
}

// tiny: amax of conv_w (block 0) and lin_w (block 1), direct store (no atomics)
__global__ void small_k(const float* __restrict__ cw, const float* __restrict__ lw, float* __restrict__ wsf) {
  __shared__ float red[256];
  const float* p = blockIdx.x ? lw : cw;
  int n = blockIdx.x ? NCLS * CC : CC * 4;
  float m = 0.f;
  for (int i = threadIdx.x; i < n; i += 256) m = fmaxf(m, fabsf(p[i]));
  red[threadIdx.x] = m; __syncthreads();
  for (int s = 128; s; s >>= 1) { if (threadIdx.x < s) red[threadIdx.x] = fmaxf(red[threadIdx.x], red[threadIdx.x + s]); __syncthreads(); }
  if (!threadIdx.x) wsf[blockIdx.x ? 5 : 1] = red[0];
}

// P1: amax(x), block partial -> bm0[blockIdx]
__global__ __launch_bounds__(256) void p1_k(const float* __restrict__ x, float* __restrict__ bm) {
  __shared__ float red4[4];
  const float4* p4 = (const float4*)x;
  long long n4 = NTOT / 4;
  float m = 0.f;
  long long i = (long long)blockIdx.x * 256 + threadIdx.x;
  long long stride = (long long)G1 * 256;
  for (; i < n4; i += stride) {
    float4 v = p4[i];
    m = fmaxf(m, fmaxf(fmaxf(fabsf(v.x), fabsf(v.y)), fmaxf(fabsf(v.z), fabsf(v.w))));
  }
  m = wred_max(m);
  if ((threadIdx.x & 63) == 0) red4[threadIdx.x >> 6] = m;
  __syncthreads();
  if (!threadIdx.x) bm[blockIdx.x] = fmaxf(fmaxf(red4[0], red4[1]), fmaxf(red4[2], red4[3]));
}

// generic single-block max-reduce of n floats -> *dst
__global__ void fin_k(const float* __restrict__ src, int n, float* __restrict__ dst) {
  __shared__ float red[256];
  float m = 0.f;
  for (int i = threadIdx.x; i < n; i += 256) m = fmaxf(m, src[i]);
  red[threadIdx.x] = m; __syncthreads();
  for (int s = 128; s; s >>= 1) { if (threadIdx.x < s) red[threadIdx.x] = fmaxf(red[threadIdx.x], red[threadIdx.x + s]); __syncthreads(); }
  if (!threadIdx.x) *dst = red[0];
}

// P2: read x fp32, quantize to int8 levels qx (store if provided), conv, amax|h|
__global__ __launch_bounds__(256) void p2_k(const float* __restrict__ x, const float* __restrict__ cw,
    const float* __restrict__ cb, const float* __restrict__ wsf,
    signed char* __restrict__ qx, float* __restrict__ bm) {
  __shared__ float red4[4];
  int tid = threadIdx.x;
  float s_x = wsf[0] / 127.f + 1e-8f, rs_x = 1.f / s_x;
  float s_w = wsf[1] / 127.f + 1e-8f;
  float s_xw = s_x * s_w;
  float m = 0.f;
  for (int row = blockIdx.x; row < ROWS; row += G2) {
    int c = row & (CC - 1);
    float wl0 = qlvl_div(cw[c * 4 + 0], s_w), wl1 = qlvl_div(cw[c * 4 + 1], s_w);
    float wl2 = qlvl_div(cw[c * 4 + 2], s_w), wl3 = qlvl_div(cw[c * 4 + 3], s_w);
    float bc = cb[c];
    const float* xr = x + 1LL * row * LL;
    int t0 = tid * 16;
    float lv[19];
    if (t0 == 0) { lv[0] = 0.f; lv[1] = 0.f; lv[2] = 0.f; }
    else {
      float4 p = *(const float4*)(xr + t0 - 4);
      lv[0] = qlvl_mul(p.y, rs_x); lv[1] = qlvl_mul(p.z, rs_x); lv[2] = qlvl_mul(p.w, rs_x);
    }
#pragma unroll
    for (int jj = 0; jj < 4; ++jj) {
      float4 v = *(const float4*)(xr + t0 + 4 * jj);
      lv[3 + 4 * jj] = qlvl_mul(v.x, rs_x); lv[4 + 4 * jj] = qlvl_mul(v.y, rs_x);
      lv[5 + 4 * jj] = qlvl_mul(v.z, rs_x); lv[6 + 4 * jj] = qlvl_mul(v.w, rs_x);
    }
    union { int4 v; signed char ch[16]; } pk;
#pragma unroll
    for (int j = 0; j < 16; ++j) {
      pk.ch[j] = (signed char)(int)lv[3 + j];
      float sum = lv[j] * wl0 + lv[j + 1] * wl1 + lv[j + 2] * wl2 + lv[j + 3] * wl3;  // exact int in fp32
      float h = fmaf(s_xw, sum, bc);
      m = fmaxf(m, fabsf(h));
    }
    if (qx) *(int4*)(qx + 1LL * row * LL + t0) = pk.v;
  }
  m = wred_max(m);
  if ((tid & 63) == 0) red4[tid >> 6] = m;
  __syncthreads();
  if (!tid) bm[blockIdx.x] = fmaxf(fmaxf(red4[0], red4[1]), fmaxf(red4[2], red4[3]));
}

// fin for conv amax + build absY table: absY[i] = |silu((i-128)*s_c)|
__global__ void finA_k(const float* __restrict__ src, int n, float* __restrict__ wsf, float* __restrict__ absY) {
  __shared__ float red[256];
  float m = 0.f;
  for (int i = threadIdx.x; i < n; i += 256) m = fmaxf(m, src[i]);
  red[threadIdx.x] = m; __syncthreads();
  for (int s = 128; s; s >>= 1) { if (threadIdx.x < s) red[threadIdx.x] = fmaxf(red[threadIdx.x], red[threadIdx.x + s]); __syncthreads(); }
  if (!threadIdx.x) wsf[2] = red[0];
  float s_c = red[0] / 127.f + 1e-8f;
  float v = (float)((int)threadIdx.x - 128) * s_c;
  float y = v * (1.f / (1.f + expf(-v)));
  absY[threadIdx.x] = fabsf(y);
}

// P3: conv from qx int8 levels (exact), conv-quant -> qc int8 store,
// amax|silu| via replicated conflict-free LDS table.
__global__ __launch_bounds__(256) void p3_k(const signed char* __restrict__ qx, const float* __restrict__ cw,
    const float* __restrict__ cb, const float* __restrict__ wsf, const float* __restrict__ absY,
    signed char* __restrict__ qc, float* __restrict__ bm) {
  __shared__ float lutR[256 * 32];
  __shared__ float red4[4];
  int tid = threadIdx.x, t31 = tid & 31;
#pragma unroll
  for (int k = 0; k < 32; ++k) lutR[tid * 32 + k] = absY[tid];
  __syncthreads();
  float s_x = wsf[0] / 127.f + 1e-8f;
  float s_w = wsf[1] / 127.f + 1e-8f;
  float s_c = wsf[2] / 127.f + 1e-8f;
  float rs_c = 1.f / s_c, s_xw = s_x * s_w;
  float m = 0.f;
  for (int row = blockIdx.x; row < ROWS; row += G3) {
    int c = row & (CC - 1);
    float wl0 = qlvl_div(cw[c * 4 + 0], s_w), wl1 = qlvl_div(cw[c * 4 + 1], s_w);
    float wl2 = qlvl_div(cw[c * 4 + 2], s_w), wl3 = qlvl_div(cw[c * 4 + 3], s_w);
    float bc = cb[c];
    const signed char* qr = qx + 1LL * row * LL;
    int t0 = tid * 16;
    float lv[19];
    if (t0 == 0) { lv[0] = 0.f; lv[1] = 0.f; lv[2] = 0.f; }
    else {
      int pv = *(const int*)(qr + t0 - 4);
      lv[0] = (float)((signed char)(pv >> 8));
      lv[1] = (float)((signed char)(pv >> 16));
      lv[2] = (float)(pv >> 24);
    }
    union { int4 v; signed char ch[16]; } in;
    in.v = *(const int4*)(qr + t0);
#pragma unroll
    for (int j = 0; j < 16; ++j) lv[3 + j] = (float)in.ch[j];
    union { int4 v; signed char ch[16]; } out;
#pragma unroll
    for (int j = 0; j < 16; ++j) {
      float sum = lv[j] * wl0 + lv[j + 1] * wl1 + lv[j + 2] * wl2 + lv[j + 3] * wl3;
      float h = fmaf(s_xw, sum, bc);
      float qf = fminf(fmaxf(rintf(h * rs_c), -128.f), 127.f);
      out.ch[j] = (signed char)(int)qf;
      m = fmaxf(m, lutR[((int)qf + 128) * 32 + t31]);
    }
    *(int4*)(qc + 1LL * row * LL + t0) = out.v;
  }
  m = wred_max(m);
  if ((tid & 63) == 0) red4[tid >> 6] = m;
  __syncthreads();
  if (!tid) bm[blockIdx.x] = fmaxf(fmaxf(red4[0], red4[1]), fmaxf(red4[2], red4[3]));
}

// P3 fallback (no qx buffer): recompute quantized x from fp32
__global__ __launch_bounds__(256) void p3b_k(const float* __restrict__ x, const float* __restrict__ cw,
    const float* __restrict__ cb, const float* __restrict__ wsf, const float* __restrict__ absY,
    signed char* __restrict__ qc, float* __restrict__ bm) {
  __shared__ float lutR[256 * 32];
  __shared__ float red4[4];
  int tid = threadIdx.x, t31 = tid & 31;
#pragma unroll
  for (int k = 0; k < 32; ++k) lutR[tid * 32 + k] = absY[tid];
  __syncthreads();
  float s_x = wsf[0] / 127.f + 1e-8f, rs_x = 1.f / s_x;
  float s_w = wsf[1] / 127.f + 1e-8f;
  float s_c = wsf[2] / 127.f + 1e-8f;
  float rs_c = 1.f / s_c, s_xw = s_x * s_w;
  float m = 0.f;
  for (int row = blockIdx.x; row < ROWS; row += G3) {
    int c = row & (CC - 1);
    float wl0 = qlvl_div(cw[c * 4 + 0], s_w), wl1 = qlvl_div(cw[c * 4 + 1], s_w);
    float wl2 = qlvl_div(cw[c * 4 + 2], s_w), wl3 = qlvl_div(cw[c * 4 + 3], s_w);
    float bc = cb[c];
    const float* xr = x + 1LL * row * LL;
    int t0 = tid * 16;
    float lv[19];
    if (t0 == 0) { lv[0] = 0.f; lv[1] = 0.f; lv[2] = 0.f; }
    else {
      float4 p = *(const float4*)(xr + t0 - 4);
      lv[0] = qlvl_mul(p.y, rs_x); lv[1] = qlvl_mul(p.z, rs_x); lv[2] = qlvl_mul(p.w, rs_x);
    }
#pragma unroll
    for (int jj = 0; jj < 4; ++jj) {
      float4 v = *(const float4*)(xr + t0 + 4 * jj);
      lv[3 + 4 * jj] = qlvl_mul(v.x, rs_x); lv[4 + 4 * jj] = qlvl_mul(v.y, rs_x);
      lv[5 + 4 * jj] = qlvl_mul(v.z, rs_x); lv[6 + 4 * jj] = qlvl_mul(v.w, rs_x);
    }
    union { int4 v; signed char ch[16]; } out;
#pragma unroll
    for (int j = 0; j < 16; ++j) {
      float sum = lv[j] * wl0 + lv[j + 1] * wl1 + lv[j + 2] * wl2 + lv[j + 3] * wl3;
      float h = fmaf(s_xw, sum, bc);
      float qf = fminf(fmaxf(rintf(h * rs_c), -128.f), 127.f);
      out.ch[j] = (signed char)(int)qf;
      m = fmaxf(m, lutR[((int)qf + 128) * 32 + t31]);
    }
    *(int4*)(qc + 1LL * row * LL + t0) = out.v;
  }
  m = wred_max(m);
  if ((tid & 63) == 0) red4[tid >> 6] = m;
  __syncthreads();
  if (!tid) bm[blockIdx.x] = fmaxf(fmaxf(red4[0], red4[1]), fmaxf(red4[2], red4[3]));
}

// fin silu amax + build pool LUT: lut2[i] = fq(fq(silu((i-128)*s_c), s1), s2)
__global__ void finL_k(const float* __restrict__ src, int n, float* __restrict__ wsf, float* __restrict__ lut2) {
  __shared__ float red[256];
  float m = 0.f;
  for (int i = threadIdx.x; i < n; i += 256) m = fmaxf(m, src[i]);
  red[threadIdx.x] = m; __syncthreads();
  for (int s = 128; s; s >>= 1) { if (threadIdx.x < s) red[threadIdx.x] = fmaxf(red[threadIdx.x], red[threadIdx.x + s]); __syncthreads(); }
  float amax_y = red[0];
  if (!threadIdx.x) wsf[3] = amax_y;
  float s_c = wsf[2] / 127.f + 1e-8f;
  float s1 = amax_y / 127.f + 1e-8f;
  float maxj = fminf(fmaxf(rintf(amax_y / s1), -128.f), 127.f);
  float s2 = (maxj * s1) / 127.f + 1e-8f;
  float v = (float)((int)threadIdx.x - 128) * s_c;
  float y = v * (1.f / (1.f + expf(-v)));
  float y1 = fq_div(y, s1);
  lut2[threadIdx.x] = fq_div(y1, s2);
}

// P5: mean-pool per row via replicated conflict-free LUT; one wave per row.
__global__ __launch_bounds__(256) void p5_k(const signed char* __restrict__ qc, const float* __restrict__ lut2,
    float* __restrict__ pooled, float* __restrict__ bm) {
  __shared__ float lutR[256 * 32];
  __shared__ float red4[4];
  int tid = threadIdx.x, t31 = tid & 31, lane = tid & 63, wid = tid >> 6;
#pragma unroll
  for (int k = 0; k < 32; ++k) lutR[tid * 32 + k] = lut2[tid];
  __syncthreads();
  float pm = 0.f;
  for (int row = blockIdx.x * 4 + wid; row < ROWS; row += G5 * 4) {
    const signed char* qr = qc + 1LL * row * LL;
    float sum = 0.f;
#pragma unroll
    for (int p = 0; p < 4; ++p) {
      union { int4 v; signed char ch[16]; } pk;
      pk.v = *(const int4*)(qr + p * 1024 + lane * 16);
#pragma unroll
      for (int k = 0; k < 16; ++k) sum += lutR[((int)pk.ch[k] + 128) * 32 + t31];
    }
    sum = wred_sum(sum);
    if (lane == 0) {
      float pv = sum * (1.f / (float)LL);
      pooled[row] = pv;
      pm = fmaxf(pm, fabsf(pv));
    }
  }
  pm = wred_max(pm);
  if (lane == 0) red4[wid] = pm;
  __syncthreads();
  if (!tid) bm[blockIdx.x] = fmaxf(fmaxf(red4[0], red4[1]), fmaxf(red4[2], red4[3]));
}

// head: logits[b,n] = sum_c fq(pooled[b,c], s_p) * fq(lw[n,c], s_l) + lb[n]
__global__ __launch_bounds__(256) void head_k(const float* __restrict__ pooled, const float* __restrict__ lw,
    const float* __restrict__ lb, const float* __restrict__ wsf, float* __restrict__ out) {
  __shared__ float red[256];
  int b = blockIdx.x / NCLS, n = blockIdx.x % NCLS;
  float s_p = wsf[4] / 127.f + 1e-8f, s_l = wsf[5] / 127.f + 1e-8f;
  float sum = 0.f;
  for (int ci = threadIdx.x; ci < CC; ci += 256)
    sum += fq_div(pooled[b * CC + ci], s_p) * fq_div(lw[n * CC + ci], s_l);
  red[threadIdx.x] = sum; __syncthreads();
  for (int s = 128; s; s >>= 1) { if (threadIdx.x < s) red[threadIdx.x] += red[threadIdx.x + s]; __syncthreads(); }
  if (!threadIdx.x) out[b * NCLS + n] = red[0] + lb[n];
}

extern "C" void kernel_launch(void* const* d_in, const int* in_sizes, int n_in,
                              void* d_out, int out_size, void* d_ws, size_t ws_size,
                              hipStream_t stream) {
  const float* x  = (const float*)d_in[0];
  const float* cw = (const float*)d_in[1];
  const float* cb = (const float*)d_in[2];
  const float* lw = (const float*)d_in[3];
  const float* lb = (const float*)d_in[4];
  float* out = (float*)d_out;
  float* wsf = (float*)d_ws;
  float* lut2   = wsf + OF_LUT2;
  float* absY   = wsf + OF_ABSY;
  float* pooled = wsf + OF_POOL;
  float* bm0 = wsf + OF_BM0;
  float* bm1 = wsf + OF_BM1;
  float* bm2 = wsf + OF_BM2;
  float* bm3 = wsf + OF_BM3;

  bool haveQX = ws_size >= OFFQ + 2ull * (size_t)NTOT;      // room for qx + qc?
  signed char* qx = (signed char*)d_ws + OFFQ;
  signed char* qc = haveQX ? qx + NTOT : qx;                // if no qx, qc lives at OFFQ

  hipLaunchKernelGGL(small_k, dim3(2), dim3(256), 0, stream, cw, lw, wsf);
  hipLaunchKernelGGL(p1_k, dim3(G1), dim3(256), 0, stream, x, bm0);
  hipLaunchKernelGGL(fin_k, dim3(1), dim3(256), 0, stream, bm0, G1, wsf + 0);
  hipLaunchKernelGGL(p2_k, dim3(G2), dim3(256), 0, stream, x, cw, cb, wsf,
                     haveQX ? qx : (signed char*)nullptr, bm1);
  hipLaunchKernelGGL(finA_k, dim3(1), dim3(256), 0, stream, bm1, G2, wsf, absY);
  if (haveQX) {
    hipLaunchKernelGGL(p3_k, dim3(G3), dim3(256), 0, stream, qx, cw, cb, wsf, absY, qc, bm2);
  } else {
    hipLaunchKernelGGL(p3b_k, dim3(G3), dim3(256), 0, stream, x, cw, cb, wsf, absY, qc, bm2);
  }
  hipLaunchKernelGGL(finL_k, dim3(1), dim3(256), 0, stream, bm2, G3, wsf, lut2);
  hipLaunchKernelGGL(p5_k, dim3(G5), dim3(256), 0, stream, qc, lut2, pooled, bm3);
  hipLaunchKernelGGL(fin_k, dim3(1), dim3(256), 0, stream, bm3, G5, wsf + 4);
  hipLaunchKernelGGL(head_k, dim3(BB * NCLS), dim3(256), 0, stream, pooled, lw, lb, wsf, out);
}